// Round 6
// baseline (217.797 us; speedup 1.0000x reference)
//
#include <hip/hip_runtime.h>
#include <hip/hip_bf16.h>
#include <math.h>

#define BB 4
#define CC 256
#define DKK 32
#define NN 4096
// 1/sqrt(32) * log2(e) — folded into q at QKV epilogue; attention uses exp2.
#define QSCALE 0.2550181864060454f

typedef __attribute__((ext_vector_type(8))) __bf16 bf16x8;
typedef __attribute__((ext_vector_type(4))) __bf16 bf16x4;
typedef __attribute__((ext_vector_type(4))) float f32x4;

// ---------------------------------------------------------------------------
// Kernel 0: fused (a) x transpose (B,C,N) fp32 -> xT (B,N,C) bf16,
//           (b) W fp32 -> bf16 Wb[320][256] (done by 80 of the blocks).
// ---------------------------------------------------------------------------
__global__ __launch_bounds__(256) void prep_kernel(
    const float* __restrict__ x, __bf16* __restrict__ xT,
    const float* __restrict__ Wq, const float* __restrict__ Wk,
    const float* __restrict__ Wv, __bf16* __restrict__ Wb)
{
    __shared__ float xs[64][68];
    const int tid = threadIdx.x;
    const int n0 = blockIdx.x * 64;
    const int c0 = blockIdx.y * 64;
    const int b  = blockIdx.z;

    // ---- wconv side-job on 80 blocks of the z==0 slice ----
    if (b == 0) {
        int unit = blockIdx.y * 64 + blockIdx.x;
        if (unit < 80) {
            int i = (unit * 256 + tid) * 4;
            int row = i >> 8, col = i & 255;
            const float* src;
            if (row < 32)      src = &Wq[row * 256 + col];
            else if (row < 64) src = &Wk[(row - 32) * 256 + col];
            else               src = &Wv[(row - 64) * 256 + col];
            float4 v = *(const float4*)src;
            Wb[i]     = (__bf16)v.x;
            Wb[i + 1] = (__bf16)v.y;
            Wb[i + 2] = (__bf16)v.z;
            Wb[i + 3] = (__bf16)v.w;
        }
    }

#pragma unroll
    for (int p = 0; p < 4; p++) {
        int cc = p * 16 + (tid >> 4);
        int nf = (tid & 15) * 4;
        float4 v = *(const float4*)&x[((size_t)(b * CC + c0 + cc)) * NN + n0 + nf];
        xs[cc][nf] = v.x; xs[cc][nf + 1] = v.y; xs[cc][nf + 2] = v.z; xs[cc][nf + 3] = v.w;
    }
    __syncthreads();
    int n = tid >> 2, cs = (tid & 3) * 16;
    bf16x8 lo, hi;
#pragma unroll
    for (int j = 0; j < 8; j++) {
        lo[j] = (__bf16)xs[cs + j][n];
        hi[j] = (__bf16)xs[cs + 8 + j][n];
    }
    size_t base = ((size_t)(b * NN + n0 + n)) * CC + c0 + cs;
    *(bf16x8*)&xT[base]     = lo;
    *(bf16x8*)&xT[base + 8] = hi;
}

// ---------------------------------------------------------------------------
// Kernel 1: QKV projection — MFMA GEMM, register-bounded depth-1 prefetch.
// Block: 32 n x 320 o; wave w -> o 80w..80w+79. Grid 128 x B.
// Outputs: q,k (B,N,32) bf16 (q pre-scaled); V TILED: [chunk n/32][c/16][16][32].
// ---------------------------------------------------------------------------
__global__ __launch_bounds__(256) void qkv_kernel(
    const __bf16* __restrict__ xT, const __bf16* __restrict__ Wb,
    const float* __restrict__ bq, const float* __restrict__ bk,
    const float* __restrict__ bv,
    __bf16* __restrict__ qws, __bf16* __restrict__ kws, __bf16* __restrict__ vws)
{
    __shared__ float scr[64][33];

    const int tid = threadIdx.x;
    const int w   = tid >> 6;
    const int l   = tid & 63;
    const int l15 = l & 15;
    const int lq  = l >> 4;
    const int n0  = blockIdx.x * 32;
    const int b   = blockIdx.y;

    const __bf16* xbase = xT + ((size_t)b * NN + n0 + l15) * CC + lq * 8;
    const __bf16* wbase = Wb + (size_t)(80 * w + l15) * CC + lq * 8;

    const f32x4 zf = {0.f, 0.f, 0.f, 0.f};
    f32x4 acc[5][2];
#pragma unroll
    for (int i = 0; i < 5; i++)
#pragma unroll
        for (int j = 0; j < 2; j++) acc[i][j] = zf;

    bf16x8 bcur[2], acur[5], bnxt[2], anxt[5];
#pragma unroll
    for (int nt = 0; nt < 2; nt++) bcur[nt] = *(const bf16x8*)(xbase + nt * 16 * CC);
#pragma unroll
    for (int ot = 0; ot < 5; ot++) acur[ot] = *(const bf16x8*)(wbase + ot * 16 * CC);

#pragma unroll
    for (int ks = 0; ks < 8; ks++) {
        if (ks < 7) {
#pragma unroll
            for (int nt = 0; nt < 2; nt++)
                bnxt[nt] = *(const bf16x8*)(xbase + nt * 16 * CC + (ks + 1) * 32);
#pragma unroll
            for (int ot = 0; ot < 5; ot++)
                anxt[ot] = *(const bf16x8*)(wbase + ot * 16 * CC + (ks + 1) * 32);
        }
#pragma unroll
        for (int ot = 0; ot < 5; ot++)
#pragma unroll
            for (int nt = 0; nt < 2; nt++)
                acc[ot][nt] = __builtin_amdgcn_mfma_f32_16x16x32_bf16(acur[ot], bcur[nt], acc[ot][nt], 0, 0, 0);
        if (ks < 7) {
#pragma unroll
            for (int nt = 0; nt < 2; nt++) bcur[nt] = bnxt[nt];
#pragma unroll
            for (int ot = 0; ot < 5; ot++) acur[ot] = anxt[ot];
        }
    }

    // epilogue: D row o = 80w + ot*16 + lq*4 + r, col n = nt*16 + l15
    __bf16* vchunk = vws + (size_t)b * CC * NN + (size_t)(n0 >> 5) * 16 * 512;
#pragma unroll
    for (int ot = 0; ot < 5; ot++) {
        int ob = 80 * w + ot * 16;
#pragma unroll
        for (int nt = 0; nt < 2; nt++) {
#pragma unroll
            for (int r = 0; r < 4; r++) {
                int o = ob + lq * 4 + r;
                int n = nt * 16 + l15;
                float val = acc[ot][nt][r];
                if (ob >= 64) {
                    int c = o - 64;
                    // tiled V: [ctile][c&15][n-in-chunk]
                    vchunk[(5 * w - 4 + ot) * 512 + (lq * 4 + r) * 32 + n] =
                        (__bf16)(val + bv[c]);
                } else if (ob < 32) {
                    scr[o][n] = (val + bq[o]) * QSCALE;
                } else {
                    scr[o][n] = val + bk[o - 32];
                }
            }
        }
    }
    __syncthreads();
    {
        int n  = tid >> 3;            // 0..31
        int d0 = (tid & 7) * 4;       // 0..28
        bf16x4 qv, kv;
#pragma unroll
        for (int j = 0; j < 4; j++) {
            qv[j] = (__bf16)scr[d0 + j][n];
            kv[j] = (__bf16)scr[32 + d0 + j][n];
        }
        size_t base = ((size_t)b * NN + n0 + n) * DKK + d0;
        *(bf16x4*)&qws[base] = qv;
        *(bf16x4*)&kws[base] = kv;
    }
}

// ---------------------------------------------------------------------------
// Kernel 2: flash attention — ZERO-BARRIER main loop.
// Block: 64 m (grid 256, 1/CU), 4 waves. Each wave REDUNDANTLY computes the
// full 64m x 32n P tile (8 KQ MFMA + 32 exp2) and round-trips it through
// WAVE-PRIVATE LDS (intra-wave lgkm deps only -> compiler can software-
// pipeline across chunks, no serial barrier chain). PV is c-split: wave w
// owns c 64w..64w+63; V is read in tiled layout (contiguous 1KB per frag).
// l-normalization is per-lane (m = lane&15 everywhere); epilogue needs no
// LDS and no __syncthreads at all.
// ---------------------------------------------------------------------------
#define PST 48                     // row stride (bf16): 96B rows, 16B-aligned
#define PWBUF (64 * PST)           // one P buffer per wave (3072 elems)

__global__ __launch_bounds__(256, 1) void attn_kernel(
    const __bf16* __restrict__ qb, const __bf16* __restrict__ kb,
    const __bf16* __restrict__ vt, const float* __restrict__ x,
    float* __restrict__ out)
{
    __shared__ __align__(16) __bf16 pbuf[4][2][PWBUF];   // 49152 B

    const int tid = threadIdx.x;
    const int w   = tid >> 6;
    const int l   = tid & 63;
    const int l15 = l & 15;
    const int lq  = l >> 4;

    // XCD swizzle: batch pinned to an XCD pair -> K/V/Q stay L2-resident
    const int beta = blockIdx.x;
    const int b    = (beta >> 1) & 3;
    const int mt   = ((beta >> 3) << 1) | (beta & 1);   // 0..63
    const int m0   = mt * 64;

    const __bf16* qbb = qb + (size_t)b * NN * DKK;
    const __bf16* kbb = kb + (size_t)b * NN * DKK;
    const __bf16* vtb = vt + (size_t)b * CC * NN;

    // q B-frags for all 4 m-tiles (m = l15 within each tile)
    bf16x8 qa[4];
#pragma unroll
    for (int af = 0; af < 4; af++)
        qa[af] = *(const bf16x8*)(qbb + (size_t)(m0 + af * 16 + l15) * DKK + lq * 8);

    __bf16* pw = &pbuf[w][0][0];
    const __bf16* kaddr = kbb + (size_t)l15 * DKK + lq * 8;          // + nc*DKK
    const __bf16* vaddr = vtb + (size_t)(w * 4) * 512 + l15 * 32 + lq * 8;  // + (ic*16+ct)*512

    const f32x4 zf = {0.f, 0.f, 0.f, 0.f};
    f32x4 acc[4][4];
#pragma unroll
    for (int i = 0; i < 4; i++)
#pragma unroll
        for (int j = 0; j < 4; j++) acc[i][j] = zf;
    float lacc[4] = {0.f, 0.f, 0.f, 0.f};

    // ---- prologue: k/V for chunk 0+1 in flight; P(0) -> buf 0 ----
    bf16x8 kA0 = *(const bf16x8*)(kaddr);
    bf16x8 kA1 = *(const bf16x8*)(kaddr + 16 * DKK);
    bf16x8 kB0 = *(const bf16x8*)(kaddr + 32 * DKK);
    bf16x8 kB1 = *(const bf16x8*)(kaddr + 48 * DKK);
    bf16x8 vA[4], vB[4];
#pragma unroll
    for (int ct = 0; ct < 4; ct++) {
        vA[ct] = *(const bf16x8*)(vaddr + (size_t)ct * 512);
        vB[ct] = *(const bf16x8*)(vaddr + (size_t)(16 + ct) * 512);
    }

    // P(0): full 64m x 32n, redundant per wave
#pragma unroll
    for (int af = 0; af < 4; af++) {
        f32x4 e0 = __builtin_amdgcn_mfma_f32_16x16x32_bf16(kA0, qa[af], zf, 0, 0, 0);
        f32x4 e1 = __builtin_amdgcn_mfma_f32_16x16x32_bf16(kA1, qa[af], zf, 0, 0, 0);
        bf16x4 p0, p1;
#pragma unroll
        for (int r = 0; r < 4; r++) {
            float v0 = __builtin_exp2f(e0[r]); lacc[af] += v0; p0[r] = (__bf16)v0;
            float v1 = __builtin_exp2f(e1[r]); lacc[af] += v1; p1[r] = (__bf16)v1;
        }
        *(bf16x4*)&pw[(af * 16 + l15) * PST + lq * 4]      = p0;
        *(bf16x4*)&pw[(af * 16 + l15) * PST + 16 + lq * 4] = p1;
    }
    kA0 = kB0; kA1 = kB1;
    kB0 = *(const bf16x8*)(kaddr + 64 * DKK);
    kB1 = *(const bf16x8*)(kaddr + 80 * DKK);

    // ---- main loop: branchless, no barriers; iteration ic does
    //      pf<-P(ic), KQ+exp->P(ic+1), PV(ic) ----
#pragma unroll 2
    for (int ic = 0; ic < 127; ic++) {
        const int cur = ic & 1;

        bf16x8 pf[4];
#pragma unroll
        for (int af = 0; af < 4; af++)
            pf[af] = *(const bf16x8*)&pw[cur * PWBUF + (af * 16 + l15) * PST + lq * 8];

        // KQ(ic+1) + exp into the other wave-private buffer
#pragma unroll
        for (int af = 0; af < 4; af++) {
            f32x4 e0 = __builtin_amdgcn_mfma_f32_16x16x32_bf16(kA0, qa[af], zf, 0, 0, 0);
            f32x4 e1 = __builtin_amdgcn_mfma_f32_16x16x32_bf16(kA1, qa[af], zf, 0, 0, 0);
            bf16x4 p0, p1;
#pragma unroll
            for (int r = 0; r < 4; r++) {
                float v0 = __builtin_exp2f(e0[r]); lacc[af] += v0; p0[r] = (__bf16)v0;
                float v1 = __builtin_exp2f(e1[r]); lacc[af] += v1; p1[r] = (__bf16)v1;
            }
            *(bf16x4*)&pw[(cur ^ 1) * PWBUF + (af * 16 + l15) * PST + lq * 4]      = p0;
            *(bf16x4*)&pw[(cur ^ 1) * PWBUF + (af * 16 + l15) * PST + 16 + lq * 4] = p1;
        }
        // rotate k, prefetch chunk ic+3 (OOB-safe: lands in adjacent ws region)
        kA0 = kB0; kA1 = kB1;
        kB0 = *(const bf16x8*)(kaddr + (size_t)(ic + 3) * 32 * DKK);
        kB1 = *(const bf16x8*)(kaddr + (size_t)((ic + 3) * 32 + 16) * DKK);

        // PV(ic): O[c][m] += V[c][n] * P[m][n]
#pragma unroll
        for (int ct = 0; ct < 4; ct++)
#pragma unroll
            for (int af = 0; af < 4; af++)
                acc[af][ct] = __builtin_amdgcn_mfma_f32_16x16x32_bf16(vA[ct], pf[af], acc[af][ct], 0, 0, 0);

        // rotate V, prefetch chunk ic+2
#pragma unroll
        for (int ct = 0; ct < 4; ct++) {
            vA[ct] = vB[ct];
            vB[ct] = *(const bf16x8*)(vaddr + (size_t)((ic + 2) * 16 + ct) * 512);
        }
    }

    // ---- peel: PV(127) ----
    {
        bf16x8 pf[4];
#pragma unroll
        for (int af = 0; af < 4; af++)
            pf[af] = *(const bf16x8*)&pw[(127 & 1) * PWBUF + (af * 16 + l15) * PST + lq * 8];
#pragma unroll
        for (int ct = 0; ct < 4; ct++)
#pragma unroll
            for (int af = 0; af < 4; af++)
                acc[af][ct] = __builtin_amdgcn_mfma_f32_16x16x32_bf16(vA[ct], pf[af], acc[af][ct], 0, 0, 0);
    }

    // ---- l: sum the 4 lq-group partials (intra-wave shuffles only) ----
#pragma unroll
    for (int af = 0; af < 4; af++) {
        lacc[af] += __shfl_xor(lacc[af], 16, 64);
        lacc[af] += __shfl_xor(lacc[af], 32, 64);
    }

    // ---- epilogue: normalize (per-lane scalar), residual, store ----
#pragma unroll
    for (int af = 0; af < 4; af++) {
        float rv = 1.0f / lacc[af];
#pragma unroll
        for (int ct = 0; ct < 4; ct++) {
#pragma unroll
            for (int r = 0; r < 4; r++) {
                int c = w * 64 + ct * 16 + lq * 4 + r;
                size_t gi = ((size_t)(b * CC + c)) * NN + m0 + af * 16 + l15;
                out[gi] = acc[af][ct][r] * rv + x[gi];
            }
        }
    }
}

extern "C" void kernel_launch(void* const* d_in, const int* in_sizes, int n_in,
                              void* d_out, int out_size, void* d_ws, size_t ws_size,
                              hipStream_t stream) {
    const float* x  = (const float*)d_in[0];
    const float* Wq = (const float*)d_in[1];
    const float* bq = (const float*)d_in[2];
    const float* Wk = (const float*)d_in[3];
    const float* bk = (const float*)d_in[4];
    const float* Wv = (const float*)d_in[5];
    const float* bv = (const float*)d_in[6];
    float* out = (float*)d_out;

    __bf16* qws = (__bf16*)d_ws;                       // B*N*32
    __bf16* kws = qws + (size_t)BB * NN * DKK;         // B*N*32
    __bf16* vws = kws + (size_t)BB * NN * DKK;         // B*C*N (tiled)
    __bf16* Wb  = vws + (size_t)BB * CC * NN;          // 320*256
    __bf16* xT  = Wb  + (size_t)320 * CC;              // B*N*C

    prep_kernel<<<dim3(64, 4, BB), 256, 0, stream>>>(x, xT, Wq, Wk, Wv, Wb);
    qkv_kernel <<<dim3(128, BB), 256, 0, stream>>>(xT, Wb, bq, bk, bv, qws, kws, vws);
    attn_kernel<<<dim3(256), 256, 0, stream>>>(qws, kws, vws, x, out);
}